// Round 4
// baseline (429.103 us; speedup 1.0000x reference)
//
#include <hip/hip_runtime.h>
#include <math.h>

#define N_ATOMS 100000
#define N_EDGES 1600000
#define NSTRUCT 64

__device__ __forceinline__ float frcp(float x) { return __builtin_amdgcn_rcpf(x); }
__device__ __forceinline__ float silu(float v) { return v * frcp(1.f + __expf(-v)); }

// ---------------- CSR build ----------------

__global__ void k_hist(const int* __restrict__ i_idx, int* __restrict__ counts) {
    int e = blockIdx.x * 256 + threadIdx.x;
    if (e < N_EDGES) atomicAdd(&counts[i_idx[e]], 1);
}

__global__ void k_blocksum(const int* __restrict__ counts, int* __restrict__ bsum) {
    __shared__ int sd[256];
    int a = blockIdx.x * 256 + threadIdx.x;
    sd[threadIdx.x] = (a < N_ATOMS) ? counts[a] : 0;
    __syncthreads();
    for (int off = 128; off > 0; off >>= 1) {
        if (threadIdx.x < off) sd[threadIdx.x] += sd[threadIdx.x + off];
        __syncthreads();
    }
    if (threadIdx.x == 0) bsum[blockIdx.x] = sd[0];
}

__global__ void k_scanb(const int* __restrict__ bsum, int* __restrict__ bpre, int nb) {
    __shared__ int sd[512];
    int t = threadIdx.x;
    int v0 = (t < nb) ? bsum[t] : 0;
    sd[t] = v0;
    __syncthreads();
    for (int off = 1; off < 512; off <<= 1) {
        int v = (t >= off) ? sd[t - off] : 0;
        __syncthreads();
        sd[t] += v;
        __syncthreads();
    }
    if (t < nb) bpre[t] = sd[t] - v0;
}

__global__ void k_rowstart(const int* __restrict__ counts, const int* __restrict__ bpre,
                           int* __restrict__ row_start, int* __restrict__ cursor) {
    __shared__ int sd[256];
    int t = threadIdx.x;
    int a = blockIdx.x * 256 + t;
    int v = (a < N_ATOMS) ? counts[a] : 0;
    sd[t] = v;
    __syncthreads();
    for (int off = 1; off < 256; off <<= 1) {
        int add = (t >= off) ? sd[t - off] : 0;
        __syncthreads();
        sd[t] += add;
        __syncthreads();
    }
    if (a < N_ATOMS) {
        int excl = sd[t] - v + bpre[blockIdx.x];
        row_start[a] = excl;
        cursor[a] = excl;
    }
}

__global__ void k_scatter(const int* __restrict__ i_idx, const int* __restrict__ j_idx,
                          int* __restrict__ cursor, int* __restrict__ ej) {
    int e = blockIdx.x * 256 + threadIdx.x;
    if (e < N_EDGES) {
        int i = i_idx[e];
        int s = atomicAdd(&cursor[i], 1);
        ej[s] = j_idx[e];
    }
}

// ---------------- pack atom data: {mx,my,mz,px},{py,pz,mnorm,species} ----------------

__global__ void k_pack(const float* __restrict__ pos, const float* __restrict__ mmv,
                       const int* __restrict__ species, float* __restrict__ packed) {
    int a = blockIdx.x * 256 + threadIdx.x;
    if (a >= N_ATOMS) return;
    float mx = mmv[a * 3 + 0], my = mmv[a * 3 + 1], mz = mmv[a * 3 + 2];
    float px = pos[a * 3 + 0], py = pos[a * 3 + 1], pz = pos[a * 3 + 2];
    float mn = sqrtf(mx * mx + my * my + mz * mz + 1e-9f);
    float4* o = (float4*)packed;
    o[a * 2 + 0] = make_float4(mx, my, mz, px);
    o[a * 2 + 1] = make_float4(py, pz, mn, (float)species[a]);
}

// ---------------- fused edge gather+compute: 8 lanes/atom, lane s owns column s ----------------
// lane s computes phi_s itself (12-coeff dot) and all w_k (needed anyway) -> no shuffles.
// seg[k][s] = sum_e w_k(e) * phi_s(e); vec[s] = sum_e phi_s(e) * rhat(e).

__global__ __launch_bounds__(256) void k_edgeacc(
    const float* __restrict__ packed, const float* __restrict__ cheb,
    const int* __restrict__ row_start, const int* __restrict__ counts,
    const int* __restrict__ ej, float* __restrict__ segbuf) {
    int tid = blockIdx.x * 256 + threadIdx.x;
    int a = tid >> 3;
    int s = tid & 7;
    if (a >= N_ATOMS) return;

    const float4* pk = (const float4*)packed;
    float4 i0 = pk[a * 2 + 0];
    float4 i1 = pk[a * 2 + 1];
    float mix = i0.x, miy = i0.y, miz = i0.z;
    float pix = i0.w, piy = i1.x, piz = i1.y;
    float mni = i1.z;
    int spi = (int)i1.w;
    float inv_mni = frcp(mni);
    float mhix = mix * inv_mni, mhiy = miy * inv_mni, mhiz = miz * inv_mni;

    float sg0 = 0.f, sg1 = 0.f, sg2 = 0.f, sg3 = 0.f;
    float sg4 = 0.f, sg5 = 0.f, sg6 = 0.f, sg7 = 0.f;
    float vcx = 0.f, vcy = 0.f, vcz = 0.f;

    int start = row_start[a], cnt = counts[a];
    const float* cbase = cheb + spi * 4 * 96 + s * 12;

    // 1-deep prefetch of next neighbor's packed data
    int jn = (cnt > 0) ? ej[start] : 0;
    float4 j0n = pk[jn * 2 + 0];
    float4 j1n = pk[jn * 2 + 1];

    for (int it = 0; it < cnt; ++it) {
        float4 a0 = j0n, a1 = j1n;
        if (it + 1 < cnt) {
            jn = ej[start + it + 1];
            j0n = pk[jn * 2 + 0];
            j1n = pk[jn * 2 + 1];
        }
        float mjx = a0.x, mjy = a0.y, mjz = a0.z;
        float rx = a0.w - pix, ry = a1.x - piy, rz = a1.y - piz;
        float mnj = a1.z;
        int spj = (int)a1.w;

        // issue this lane's coeff loads early (6KB table, L1-resident)
        const float4* c4 = (const float4*)(cbase + spj * 96);
        float4 c0 = c4[0], c1 = c4[1], c2 = c4[2];

        float d = sqrtf(rx * rx + ry * ry + rz * rz + 1e-9f);
        float invd = frcp(d);
        float rhx = rx * invd, rhy = ry * invd, rhz = rz * invd;

        float x = d * (1.f / 3.f) - 1.f;
        x = fminf(fmaxf(x, -1.f), 1.f);
        float x2 = 2.f * x;
        float T0 = 1.f, T1 = x;
        float T2 = x2 * T1 - T0, T3 = x2 * T2 - T1, T4 = x2 * T3 - T2, T5 = x2 * T4 - T3;
        float T6 = x2 * T5 - T4, T7 = x2 * T6 - T5, T8 = x2 * T7 - T6, T9 = x2 * T8 - T7;
        float T10 = x2 * T9 - T8, T11 = x2 * T10 - T9;
        float fcut = (d < 6.f) ? 0.5f * (__cosf(d * 0.52359877559829887f) + 1.f) : 0.f;

        float phis = c0.x * T0 + c0.y * T1 + c0.z * T2 + c0.w * T3;
        phis += c1.x * T4 + c1.y * T5 + c1.z * T6 + c1.w * T7;
        phis += c2.x * T8 + c2.y * T9 + c2.z * T10 + c2.w * T11;
        phis *= fcut;

        float invmnj = frcp(mnj);
        float mhjx = mjx * invmnj, mhjy = mjy * invmnj, mhjz = mjz * invmnj;
        float w1 = mix * mjx + miy * mjy + miz * mjz;
        float dhi = mhix * rhx + mhiy * rhy + mhiz * rhz;
        float dhj = mhjx * rhx + mhjy * rhy + mhjz * rhz;
        float w2 = dhi * dhi, w3 = dhj * dhj;
        float cx = miy * mjz - miz * mjy;
        float cy = miz * mjx - mix * mjz;
        float cz = mix * mjy - miy * mjx;
        float w4 = rhx * cx + rhy * cy + rhz * cz;
        float w6 = (mhix * mhjx + mhiy * mhjy + mhiz * mhjz) * mnj;
        float w7 = mnj * mnj;

        sg0 += phis;
        sg1 = fmaf(w1, phis, sg1);
        sg2 = fmaf(w2, phis, sg2);
        sg3 = fmaf(w3, phis, sg3);
        sg4 = fmaf(w4, phis, sg4);
        sg5 = fmaf(mnj, phis, sg5);
        sg6 = fmaf(w6, phis, sg6);
        sg7 = fmaf(w7, phis, sg7);
        vcx = fmaf(phis, rhx, vcx);
        vcy = fmaf(phis, rhy, vcy);
        vcz = fmaf(phis, rhz, vcz);
    }

    float* o = segbuf + (size_t)a * 72;
    o[0 * 8 + s] = sg0; o[1 * 8 + s] = sg1; o[2 * 8 + s] = sg2; o[3 * 8 + s] = sg3;
    o[4 * 8 + s] = sg4; o[5 * 8 + s] = sg5; o[6 * 8 + s] = sg6; o[7 * 8 + s] = sg7;
    o[64 + s] = vcx * vcx + vcy * vcy + vcz * vcz;
}

// ---------------- structure MLP: thread=atom, weights via uniform s_load ----------------

__global__ __launch_bounds__(256) void k_struct(
    const float* __restrict__ segbuf, const int* __restrict__ species,
    const int* __restrict__ batch, const float* __restrict__ embt,
    const float* __restrict__ shift,
    const float* __restrict__ Ws1, const float* __restrict__ bs1,
    const float* __restrict__ Ws2, const float* __restrict__ bs2,
    const float* __restrict__ Ws3, const float* __restrict__ bs3,
    float* __restrict__ out) {
    __shared__ float spart[NSTRUCT];
    int t = threadIdx.x;
    if (t < NSTRUCT) spart[t] = 0.f;
    __syncthreads();

    int a = blockIdx.x * 256 + t;
    if (a < N_ATOMS) {
        const float4* sb4 = (const float4*)(segbuf + (size_t)a * 72);
        float4 v0 = sb4[0], v1 = sb4[1];    // A row
        float4 v2 = sb4[16], v3 = sb4[17];  // |vec|^2
        int spi = species[a];
        const float4* e4 = (const float4*)(embt + spi * 16);
        float4 e0 = e4[0], e1 = e4[1], e2 = e4[2], e3 = e4[3];
        float x[32] = {v0.x, v0.y, v0.z, v0.w, v1.x, v1.y, v1.z, v1.w,
                       v2.x, v2.y, v2.z, v2.w, v3.x, v3.y, v3.z, v3.w,
                       e0.x, e0.y, e0.z, e0.w, e1.x, e1.y, e1.z, e1.w,
                       e2.x, e2.y, e2.z, e2.w, e3.x, e3.y, e3.z, e3.w};

        float h1[64];
#pragma unroll
        for (int o = 0; o < 64; o++) h1[o] = bs1[o];
#pragma unroll
        for (int k = 0; k < 32; k++) {
            float xv = x[k];
#pragma unroll
            for (int o = 0; o < 64; o++) h1[o] = fmaf(xv, Ws1[k * 64 + o], h1[o]);
        }
#pragma unroll
        for (int o = 0; o < 64; o++) h1[o] = silu(h1[o]);

        float h2[64];
#pragma unroll
        for (int o = 0; o < 64; o++) h2[o] = bs2[o];
#pragma unroll
        for (int k = 0; k < 64; k++) {
            float xv = h1[k];
#pragma unroll
            for (int o = 0; o < 64; o++) h2[o] = fmaf(xv, Ws2[k * 64 + o], h2[o]);
        }
        float e_struct = bs3[0] + shift[spi];
#pragma unroll
        for (int o = 0; o < 64; o++) e_struct = fmaf(silu(h2[o]), Ws3[o], e_struct);
        atomicAdd(&spart[batch[a]], e_struct);
    }
    __syncthreads();
    if (t < NSTRUCT) {
        float v = spart[t];
        if (v != 0.f) atomicAdd(&out[t], v);
    }
}

// ---------------- magnetic MLP: wave=head (readfirstlane), weights via uniform s_load ----------------

__global__ __launch_bounds__(576) void k_mag(
    const float* __restrict__ segbuf, const float* __restrict__ packed,
    const int* __restrict__ species, const int* __restrict__ batch,
    const float* __restrict__ embt,
    const float* __restrict__ Wm1, const float* __restrict__ bm1,
    const float* __restrict__ Wm2, const float* __restrict__ bm2,
    const float* __restrict__ Wm3, const float* __restrict__ bm3,
    float* __restrict__ out) {
    __shared__ float spart[NSTRUCT];
    int t = threadIdx.x;
    if (t < NSTRUCT) spart[t] = 0.f;
    __syncthreads();

    int h = __builtin_amdgcn_readfirstlane((int)(threadIdx.x >> 6));  // wave-uniform head
    int l = t & 63;
    int a = blockIdx.x * 64 + l;
    if (a < N_ATOMS) {
        int kk = (h <= 5) ? h : (h - 1);
        const float4* sb4 = (const float4*)(segbuf + (size_t)a * 72 + kk * 8);
        float4 s0 = sb4[0], s1 = sb4[1];
        float amp = (h == 0 || h == 5) ? packed[a * 8 + 6] : 1.f;
        int spi = species[a];
        const float4* e4 = (const float4*)(embt + spi * 16);
        float4 e0 = e4[0], e1 = e4[1], e2 = e4[2], e3 = e4[3];
        float x[24] = {s0.x * amp, s0.y * amp, s0.z * amp, s0.w * amp,
                       s1.x * amp, s1.y * amp, s1.z * amp, s1.w * amp,
                       e0.x, e0.y, e0.z, e0.w, e1.x, e1.y, e1.z, e1.w,
                       e2.x, e2.y, e2.z, e2.w, e3.x, e3.y, e3.z, e3.w};

        const float* wb1 = Wm1 + h * 768;   // uniform base
        float hm1[32];
#pragma unroll
        for (int o = 0; o < 32; o++) hm1[o] = bm1[h * 32 + o];
#pragma unroll
        for (int d = 0; d < 24; d++) {
            float xv = x[d];
#pragma unroll
            for (int o = 0; o < 32; o++) hm1[o] = fmaf(xv, wb1[d * 32 + o], hm1[o]);
        }
#pragma unroll
        for (int o = 0; o < 32; o++) hm1[o] = silu(hm1[o]);

        const float* wb2 = Wm2 + h * 1024;  // uniform base
        float h2[32];
#pragma unroll
        for (int o = 0; o < 32; o++) h2[o] = bm2[h * 32 + o];
#pragma unroll
        for (int d = 0; d < 32; d++) {
            float xv = hm1[d];
#pragma unroll
            for (int o = 0; o < 32; o++) h2[o] = fmaf(xv, wb2[d * 32 + o], h2[o]);
        }
        float e_head = bm3[h];
#pragma unroll
        for (int o = 0; o < 32; o++) e_head = fmaf(silu(h2[o]), Wm3[h * 32 + o], e_head);
        atomicAdd(&spart[batch[a]], e_head);
    }
    __syncthreads();
    if (t < NSTRUCT) {
        float v = spart[t];
        if (v != 0.f) atomicAdd(&out[t], v);
    }
}

// ---------------- launch ----------------

extern "C" void kernel_launch(void* const* d_in, const int* in_sizes, int n_in,
                              void* d_out, int out_size, void* d_ws, size_t ws_size,
                              hipStream_t stream) {
    const float* pos   = (const float*)d_in[0];
    const float* mmv   = (const float*)d_in[1];
    const int* species = (const int*)d_in[2];
    const int* i_idx   = (const int*)d_in[3];
    const int* j_idx   = (const int*)d_in[4];
    const int* batch   = (const int*)d_in[5];
    const float* cheb  = (const float*)d_in[6];
    const float* embt  = (const float*)d_in[7];
    const float* shift = (const float*)d_in[8];
    const float* Ws1 = (const float*)d_in[9];
    const float* bs1 = (const float*)d_in[10];
    const float* Ws2 = (const float*)d_in[11];
    const float* bs2 = (const float*)d_in[12];
    const float* Ws3 = (const float*)d_in[13];
    const float* bs3 = (const float*)d_in[14];
    const float* Wm1 = (const float*)d_in[15];
    const float* bm1 = (const float*)d_in[16];
    const float* Wm2 = (const float*)d_in[17];
    const float* bm2 = (const float*)d_in[18];
    const float* Wm3 = (const float*)d_in[19];
    const float* bm3 = (const float*)d_in[20];
    float* out = (float*)d_out;

    char* ws = (char*)d_ws;
    int* counts    = (int*)(ws + 0);          // 400 KB
    int* row_start = (int*)(ws + 400384);
    int* cursor    = (int*)(ws + 800768);
    int* bsum      = (int*)(ws + 1201152);
    int* bpre      = (int*)(ws + 1202816);
    float* packed  = (float*)(ws + 1204480);  // 3.2 MB
    int* ej        = (int*)(ws + 4404480);    // 6.4 MB
    float* segbuf  = (float*)(ws + 10804480); // 28.8 MB (end ~39.6 MB)

    const int NB_ATOM = (N_ATOMS + 255) / 256;   // 391
    const int NB_EDGE = (N_EDGES + 255) / 256;   // 6250
    const int NB_A64  = (N_ATOMS + 63) / 64;     // 1563

    hipMemsetAsync(counts, 0, N_ATOMS * sizeof(int), stream);
    hipMemsetAsync(out, 0, NSTRUCT * sizeof(float), stream);

    k_pack<<<NB_ATOM, 256, 0, stream>>>(pos, mmv, species, packed);
    k_hist<<<NB_EDGE, 256, 0, stream>>>(i_idx, counts);
    k_blocksum<<<NB_ATOM, 256, 0, stream>>>(counts, bsum);
    k_scanb<<<1, 512, 0, stream>>>(bsum, bpre, NB_ATOM);
    k_rowstart<<<NB_ATOM, 256, 0, stream>>>(counts, bpre, row_start, cursor);
    k_scatter<<<NB_EDGE, 256, 0, stream>>>(i_idx, j_idx, cursor, ej);
    k_edgeacc<<<(N_ATOMS * 8 + 255) / 256, 256, 0, stream>>>(packed, cheb, row_start, counts, ej, segbuf);
    k_struct<<<NB_ATOM, 256, 0, stream>>>(segbuf, species, batch, embt, shift,
                                          Ws1, bs1, Ws2, bs2, Ws3, bs3, out);
    k_mag<<<NB_A64, 576, 0, stream>>>(segbuf, packed, species, batch, embt,
                                      Wm1, bm1, Wm2, bm2, Wm3, bm3, out);
}

// Round 5
// 362.042 us; speedup vs baseline: 1.1852x; 1.1852x over previous
//
#include <hip/hip_runtime.h>
#include <math.h>

#define N_ATOMS 100000
#define N_EDGES 1600000
#define NSTRUCT 64

__device__ __forceinline__ float frcp(float x) { return __builtin_amdgcn_rcpf(x); }
__device__ __forceinline__ float silu(float v) { return v * frcp(1.f + __expf(-v)); }

__device__ __forceinline__ unsigned pack2(float a, float b) {
    unsigned ua = __float_as_uint(a), ub = __float_as_uint(b);
    ua = (ua + 0x7fffu + ((ua >> 16) & 1u)) >> 16;
    ub = (ub + 0x7fffu + ((ub >> 16) & 1u)) >> 16;
    return ua | (ub << 16);
}
__device__ __forceinline__ float lo16(unsigned u) { return __uint_as_float(u << 16); }
__device__ __forceinline__ float hi16(unsigned u) { return __uint_as_float(u & 0xffff0000u); }

// ---------------- CSR build ----------------

__global__ void k_hist(const int* __restrict__ i_idx, int* __restrict__ counts) {
    int e = blockIdx.x * 256 + threadIdx.x;
    if (e < N_EDGES) atomicAdd(&counts[i_idx[e]], 1);
}

__global__ void k_blocksum(const int* __restrict__ counts, int* __restrict__ bsum) {
    __shared__ int sd[256];
    int a = blockIdx.x * 256 + threadIdx.x;
    sd[threadIdx.x] = (a < N_ATOMS) ? counts[a] : 0;
    __syncthreads();
    for (int off = 128; off > 0; off >>= 1) {
        if (threadIdx.x < off) sd[threadIdx.x] += sd[threadIdx.x + off];
        __syncthreads();
    }
    if (threadIdx.x == 0) bsum[blockIdx.x] = sd[0];
}

__global__ void k_scanb(const int* __restrict__ bsum, int* __restrict__ bpre, int nb) {
    __shared__ int sd[512];
    int t = threadIdx.x;
    int v0 = (t < nb) ? bsum[t] : 0;
    sd[t] = v0;
    __syncthreads();
    for (int off = 1; off < 512; off <<= 1) {
        int v = (t >= off) ? sd[t - off] : 0;
        __syncthreads();
        sd[t] += v;
        __syncthreads();
    }
    if (t < nb) bpre[t] = sd[t] - v0;
}

__global__ void k_rowstart(const int* __restrict__ counts, const int* __restrict__ bpre,
                           int* __restrict__ row_start, int* __restrict__ cursor) {
    __shared__ int sd[256];
    int t = threadIdx.x;
    int a = blockIdx.x * 256 + t;
    int v = (a < N_ATOMS) ? counts[a] : 0;
    sd[t] = v;
    __syncthreads();
    for (int off = 1; off < 256; off <<= 1) {
        int add = (t >= off) ? sd[t - off] : 0;
        __syncthreads();
        sd[t] += add;
        __syncthreads();
    }
    if (a < N_ATOMS) {
        int excl = sd[t] - v + bpre[blockIdx.x];
        row_start[a] = excl;
        cursor[a] = excl;
    }
}

// ---------------- pack atom data: {mx,my,mz,px},{py,pz,mnorm,species} ----------------

__global__ void k_pack(const float* __restrict__ pos, const float* __restrict__ mmv,
                       const int* __restrict__ species, float* __restrict__ packed) {
    int a = blockIdx.x * 256 + threadIdx.x;
    if (a >= N_ATOMS) return;
    float mx = mmv[a * 3 + 0], my = mmv[a * 3 + 1], mz = mmv[a * 3 + 2];
    float px = pos[a * 3 + 0], py = pos[a * 3 + 1], pz = pos[a * 3 + 2];
    float mn = sqrtf(mx * mx + my * my + mz * mz + 1e-9f);
    float4* o = (float4*)packed;
    o[a * 2 + 0] = make_float4(mx, my, mz, px);
    o[a * 2 + 1] = make_float4(py, pz, mn, (float)species[a]);
}

// ---------------- phase A: per-edge compute, write ONE full 64B aligned record ----------------
// record: [0,32) phi f32 x8 | [32,48) bf16 {w1,w2,w3,w4,mnj,w6,w7,rhx} | [48,52) bf16 {rhy,rhz} | [52,64) zero pad

__global__ __launch_bounds__(256) void k_edges(
    const float* __restrict__ packed, const float* __restrict__ cheb,
    const int* __restrict__ i_idx, const int* __restrict__ j_idx,
    int* __restrict__ cursor, char* __restrict__ recbuf) {
    int e = blockIdx.x * 256 + threadIdx.x;
    if (e >= N_EDGES) return;
    int i = i_idx[e], j = j_idx[e];
    const float4* pk = (const float4*)packed;
    float4 i0 = pk[i * 2 + 0], i1 = pk[i * 2 + 1];
    float4 j0 = pk[j * 2 + 0], j1 = pk[j * 2 + 1];

    float mix = i0.x, miy = i0.y, miz = i0.z;
    float mjx = j0.x, mjy = j0.y, mjz = j0.z;
    float rx = j0.w - i0.w, ry = j1.x - i1.x, rz = j1.y - i1.y;
    float mni = i1.z, mnj = j1.z;
    int spi = (int)i1.w, spj = (int)j1.w;

    float d = sqrtf(rx * rx + ry * ry + rz * rz + 1e-9f);
    float invd = frcp(d);
    float rhx = rx * invd, rhy = ry * invd, rhz = rz * invd;

    float x = d * (1.f / 3.f) - 1.f;
    x = fminf(fmaxf(x, -1.f), 1.f);
    float x2 = 2.f * x;
    float T[12];
    T[0] = 1.f; T[1] = x;
#pragma unroll
    for (int k = 2; k < 12; k++) T[k] = x2 * T[k - 1] - T[k - 2];
    float fcut = (d < 6.f) ? 0.5f * (__cosf(d * 0.52359877559829887f) + 1.f) : 0.f;

    const float* crow = cheb + (spi * 4 + spj) * 96;
    float phi[8];
#pragma unroll
    for (int n = 0; n < 8; n++) {
        const float4* c4 = (const float4*)(crow + n * 12);
        float4 c0 = c4[0], c1 = c4[1], c2 = c4[2];
        float acc = c0.x * T[0] + c0.y * T[1] + c0.z * T[2] + c0.w * T[3];
        acc += c1.x * T[4] + c1.y * T[5] + c1.z * T[6] + c1.w * T[7];
        acc += c2.x * T[8] + c2.y * T[9] + c2.z * T[10] + c2.w * T[11];
        phi[n] = acc * fcut;
    }

    float inv_mni = frcp(mni), inv_mnj = frcp(mnj);
    float mhix = mix * inv_mni, mhiy = miy * inv_mni, mhiz = miz * inv_mni;
    float mhjx = mjx * inv_mnj, mhjy = mjy * inv_mnj, mhjz = mjz * inv_mnj;
    float w1 = mix * mjx + miy * mjy + miz * mjz;
    float dhi = mhix * rhx + mhiy * rhy + mhiz * rhz;
    float dhj = mhjx * rhx + mhjy * rhy + mhjz * rhz;
    float w2 = dhi * dhi, w3 = dhj * dhj;
    float cx = miy * mjz - miz * mjy;
    float cy = miz * mjx - mix * mjz;
    float cz = mix * mjy - miy * mjx;
    float w4 = rhx * cx + rhy * cy + rhz * cz;
    float w6 = (mhix * mhjx + mhiy * mhjy + mhiz * mhjz) * mnj;
    float w7 = mnj * mnj;

    int slot = atomicAdd(&cursor[i], 1);
    char* rp = recbuf + (size_t)slot * 64;
    *(float4*)(rp +  0) = make_float4(phi[0], phi[1], phi[2], phi[3]);
    *(float4*)(rp + 16) = make_float4(phi[4], phi[5], phi[6], phi[7]);
    *(uint4*)(rp + 32) = make_uint4(pack2(w1, w2), pack2(w3, w4),
                                    pack2(mnj, w6), pack2(w7, rhx));
    *(uint4*)(rp + 48) = make_uint4(pack2(rhy, rhz), 0u, 0u, 0u);
}

// ---------------- phase B: 8 lanes/atom, lane s owns phi-column s; streaming reads ----------------

__global__ __launch_bounds__(256) void k_reduce(
    const char* __restrict__ recbuf, const int* __restrict__ row_start,
    const int* __restrict__ counts, float* __restrict__ segbuf) {
    int tid = blockIdx.x * 256 + threadIdx.x;
    int a = tid >> 3;
    int s = tid & 7;
    if (a >= N_ATOMS) return;

    int start = row_start[a], cnt = counts[a];

    float sg0 = 0.f, sg1 = 0.f, sg2 = 0.f, sg3 = 0.f;
    float sg4 = 0.f, sg5 = 0.f, sg6 = 0.f, sg7 = 0.f;
    float vcx = 0.f, vcy = 0.f, vcz = 0.f;

    for (int it = 0; it < cnt; ++it) {
        const char* rp = recbuf + (size_t)(start + it) * 64;
        float phis = *(const float*)(rp + s * 4);       // coalesced 32B across group
        uint4 wq = *(const uint4*)(rp + 32);            // broadcast (same line, L1 hit)
        unsigned rq = *(const unsigned*)(rp + 48);

        float w1 = lo16(wq.x), w2 = hi16(wq.x);
        float w3 = lo16(wq.y), w4 = hi16(wq.y);
        float w5 = lo16(wq.z), w6 = hi16(wq.z);
        float w7 = lo16(wq.w), rhx = hi16(wq.w);
        float rhy = lo16(rq), rhz = hi16(rq);

        sg0 += phis;
        sg1 = fmaf(w1, phis, sg1);
        sg2 = fmaf(w2, phis, sg2);
        sg3 = fmaf(w3, phis, sg3);
        sg4 = fmaf(w4, phis, sg4);
        sg5 = fmaf(w5, phis, sg5);
        sg6 = fmaf(w6, phis, sg6);
        sg7 = fmaf(w7, phis, sg7);
        vcx = fmaf(phis, rhx, vcx);
        vcy = fmaf(phis, rhy, vcy);
        vcz = fmaf(phis, rhz, vcz);
    }

    float* o = segbuf + (size_t)a * 72;
    o[0 * 8 + s] = sg0; o[1 * 8 + s] = sg1; o[2 * 8 + s] = sg2; o[3 * 8 + s] = sg3;
    o[4 * 8 + s] = sg4; o[5 * 8 + s] = sg5; o[6 * 8 + s] = sg6; o[7 * 8 + s] = sg7;
    o[64 + s] = vcx * vcx + vcy * vcy + vcz * vcz;
}

// ---------------- structure MLP: thread=atom, weights via uniform s_load ----------------

__global__ __launch_bounds__(256) void k_struct(
    const float* __restrict__ segbuf, const int* __restrict__ species,
    const int* __restrict__ batch, const float* __restrict__ embt,
    const float* __restrict__ shift,
    const float* __restrict__ Ws1, const float* __restrict__ bs1,
    const float* __restrict__ Ws2, const float* __restrict__ bs2,
    const float* __restrict__ Ws3, const float* __restrict__ bs3,
    float* __restrict__ out) {
    __shared__ float spart[NSTRUCT];
    int t = threadIdx.x;
    if (t < NSTRUCT) spart[t] = 0.f;
    __syncthreads();

    int a = blockIdx.x * 256 + t;
    if (a < N_ATOMS) {
        const float4* sb4 = (const float4*)(segbuf + (size_t)a * 72);
        float4 v0 = sb4[0], v1 = sb4[1];    // A row
        float4 v2 = sb4[16], v3 = sb4[17];  // |vec|^2
        int spi = species[a];
        const float4* e4 = (const float4*)(embt + spi * 16);
        float4 e0 = e4[0], e1 = e4[1], e2 = e4[2], e3 = e4[3];
        float x[32] = {v0.x, v0.y, v0.z, v0.w, v1.x, v1.y, v1.z, v1.w,
                       v2.x, v2.y, v2.z, v2.w, v3.x, v3.y, v3.z, v3.w,
                       e0.x, e0.y, e0.z, e0.w, e1.x, e1.y, e1.z, e1.w,
                       e2.x, e2.y, e2.z, e2.w, e3.x, e3.y, e3.z, e3.w};

        float h1[64];
#pragma unroll
        for (int o = 0; o < 64; o++) h1[o] = bs1[o];
#pragma unroll
        for (int k = 0; k < 32; k++) {
            float xv = x[k];
#pragma unroll
            for (int o = 0; o < 64; o++) h1[o] = fmaf(xv, Ws1[k * 64 + o], h1[o]);
        }
#pragma unroll
        for (int o = 0; o < 64; o++) h1[o] = silu(h1[o]);

        float h2[64];
#pragma unroll
        for (int o = 0; o < 64; o++) h2[o] = bs2[o];
#pragma unroll
        for (int k = 0; k < 64; k++) {
            float xv = h1[k];
#pragma unroll
            for (int o = 0; o < 64; o++) h2[o] = fmaf(xv, Ws2[k * 64 + o], h2[o]);
        }
        float e_struct = bs3[0] + shift[spi];
#pragma unroll
        for (int o = 0; o < 64; o++) e_struct = fmaf(silu(h2[o]), Ws3[o], e_struct);
        atomicAdd(&spart[batch[a]], e_struct);
    }
    __syncthreads();
    if (t < NSTRUCT) {
        float v = spart[t];
        if (v != 0.f) atomicAdd(&out[t], v);
    }
}

// ---------------- magnetic MLP: wave=head (readfirstlane), weights via uniform s_load ----------------

__global__ __launch_bounds__(576) void k_mag(
    const float* __restrict__ segbuf, const float* __restrict__ packed,
    const int* __restrict__ species, const int* __restrict__ batch,
    const float* __restrict__ embt,
    const float* __restrict__ Wm1, const float* __restrict__ bm1,
    const float* __restrict__ Wm2, const float* __restrict__ bm2,
    const float* __restrict__ Wm3, const float* __restrict__ bm3,
    float* __restrict__ out) {
    __shared__ float spart[NSTRUCT];
    int t = threadIdx.x;
    if (t < NSTRUCT) spart[t] = 0.f;
    __syncthreads();

    int h = __builtin_amdgcn_readfirstlane((int)(threadIdx.x >> 6));  // wave-uniform head
    int l = t & 63;
    int a = blockIdx.x * 64 + l;
    if (a < N_ATOMS) {
        int kk = (h <= 5) ? h : (h - 1);
        const float4* sb4 = (const float4*)(segbuf + (size_t)a * 72 + kk * 8);
        float4 s0 = sb4[0], s1 = sb4[1];
        float amp = (h == 0 || h == 5) ? packed[a * 8 + 6] : 1.f;
        int spi = species[a];
        const float4* e4 = (const float4*)(embt + spi * 16);
        float4 e0 = e4[0], e1 = e4[1], e2 = e4[2], e3 = e4[3];
        float x[24] = {s0.x * amp, s0.y * amp, s0.z * amp, s0.w * amp,
                       s1.x * amp, s1.y * amp, s1.z * amp, s1.w * amp,
                       e0.x, e0.y, e0.z, e0.w, e1.x, e1.y, e1.z, e1.w,
                       e2.x, e2.y, e2.z, e2.w, e3.x, e3.y, e3.z, e3.w};

        const float* wb1 = Wm1 + h * 768;   // uniform base
        float hm1[32];
#pragma unroll
        for (int o = 0; o < 32; o++) hm1[o] = bm1[h * 32 + o];
#pragma unroll
        for (int d = 0; d < 24; d++) {
            float xv = x[d];
#pragma unroll
            for (int o = 0; o < 32; o++) hm1[o] = fmaf(xv, wb1[d * 32 + o], hm1[o]);
        }
#pragma unroll
        for (int o = 0; o < 32; o++) hm1[o] = silu(hm1[o]);

        const float* wb2 = Wm2 + h * 1024;  // uniform base
        float h2[32];
#pragma unroll
        for (int o = 0; o < 32; o++) h2[o] = bm2[h * 32 + o];
#pragma unroll
        for (int d = 0; d < 32; d++) {
            float xv = hm1[d];
#pragma unroll
            for (int o = 0; o < 32; o++) h2[o] = fmaf(xv, wb2[d * 32 + o], h2[o]);
        }
        float e_head = bm3[h];
#pragma unroll
        for (int o = 0; o < 32; o++) e_head = fmaf(silu(h2[o]), Wm3[h * 32 + o], e_head);
        atomicAdd(&spart[batch[a]], e_head);
    }
    __syncthreads();
    if (t < NSTRUCT) {
        float v = spart[t];
        if (v != 0.f) atomicAdd(&out[t], v);
    }
}

// ---------------- launch ----------------

extern "C" void kernel_launch(void* const* d_in, const int* in_sizes, int n_in,
                              void* d_out, int out_size, void* d_ws, size_t ws_size,
                              hipStream_t stream) {
    const float* pos   = (const float*)d_in[0];
    const float* mmv   = (const float*)d_in[1];
    const int* species = (const int*)d_in[2];
    const int* i_idx   = (const int*)d_in[3];
    const int* j_idx   = (const int*)d_in[4];
    const int* batch   = (const int*)d_in[5];
    const float* cheb  = (const float*)d_in[6];
    const float* embt  = (const float*)d_in[7];
    const float* shift = (const float*)d_in[8];
    const float* Ws1 = (const float*)d_in[9];
    const float* bs1 = (const float*)d_in[10];
    const float* Ws2 = (const float*)d_in[11];
    const float* bs2 = (const float*)d_in[12];
    const float* Ws3 = (const float*)d_in[13];
    const float* bs3 = (const float*)d_in[14];
    const float* Wm1 = (const float*)d_in[15];
    const float* bm1 = (const float*)d_in[16];
    const float* Wm2 = (const float*)d_in[17];
    const float* bm2 = (const float*)d_in[18];
    const float* Wm3 = (const float*)d_in[19];
    const float* bm3 = (const float*)d_in[20];
    float* out = (float*)d_out;

    char* ws = (char*)d_ws;
    int* counts    = (int*)(ws + 0);          // 400 KB
    int* row_start = (int*)(ws + 400384);
    int* cursor    = (int*)(ws + 800768);
    int* bsum      = (int*)(ws + 1201152);
    int* bpre      = (int*)(ws + 1202816);
    float* packed  = (float*)(ws + 1204480);  // 3.2 MB
    float* segbuf  = (float*)(ws + 4404480);  // 28.8 MB
    char* recbuf   = ws + 33204480;           // 102.4 MB, 64B aligned (end ~135.6 MB)

    const int NB_ATOM = (N_ATOMS + 255) / 256;   // 391
    const int NB_EDGE = (N_EDGES + 255) / 256;   // 6250
    const int NB_A64  = (N_ATOMS + 63) / 64;     // 1563

    hipMemsetAsync(counts, 0, N_ATOMS * sizeof(int), stream);
    hipMemsetAsync(out, 0, NSTRUCT * sizeof(float), stream);

    k_pack<<<NB_ATOM, 256, 0, stream>>>(pos, mmv, species, packed);
    k_hist<<<NB_EDGE, 256, 0, stream>>>(i_idx, counts);
    k_blocksum<<<NB_ATOM, 256, 0, stream>>>(counts, bsum);
    k_scanb<<<1, 512, 0, stream>>>(bsum, bpre, NB_ATOM);
    k_rowstart<<<NB_ATOM, 256, 0, stream>>>(counts, bpre, row_start, cursor);
    k_edges<<<NB_EDGE, 256, 0, stream>>>(packed, cheb, i_idx, j_idx, cursor, recbuf);
    k_reduce<<<(N_ATOMS * 8 + 255) / 256, 256, 0, stream>>>(recbuf, row_start, counts, segbuf);
    k_struct<<<NB_ATOM, 256, 0, stream>>>(segbuf, species, batch, embt, shift,
                                          Ws1, bs1, Ws2, bs2, Ws3, bs3, out);
    k_mag<<<NB_A64, 576, 0, stream>>>(segbuf, packed, species, batch, embt,
                                      Wm1, bm1, Wm2, bm2, Wm3, bm3, out);
}

// Round 6
// 291.700 us; speedup vs baseline: 1.4710x; 1.2411x over previous
//
#include <hip/hip_runtime.h>
#include <math.h>

#define N_ATOMS 100000
#define N_EDGES 1600000
#define NSTRUCT 64
#define NBUCK 391      // ceil(N_ATOMS/256) buckets of 256 atoms
#define APB 256        // atoms per bucket
#define EPB 4096       // edges per block in bucket passes
#define BCAP 6144      // LDS staging cap per bucket (mean 4092, sigma 64)

__device__ __forceinline__ float frcp(float x) { return __builtin_amdgcn_rcpf(x); }
__device__ __forceinline__ float silu(float v) { return v * frcp(1.f + __expf(-v)); }

__device__ __forceinline__ unsigned pack2(float a, float b) {
    unsigned ua = __float_as_uint(a), ub = __float_as_uint(b);
    ua = (ua + 0x7fffu + ((ua >> 16) & 1u)) >> 16;
    ub = (ub + 0x7fffu + ((ub >> 16) & 1u)) >> 16;
    return ua | (ub << 16);
}
__device__ __forceinline__ float lo16(unsigned u) { return __uint_as_float(u << 16); }
__device__ __forceinline__ float hi16(unsigned u) { return __uint_as_float(u & 0xffff0000u); }

// ---------------- pack atom data: {mx,my,mz,px},{py,pz,mnorm,species} ----------------

__global__ void k_pack(const float* __restrict__ pos, const float* __restrict__ mmv,
                       const int* __restrict__ species, float* __restrict__ packed) {
    int a = blockIdx.x * 256 + threadIdx.x;
    if (a >= N_ATOMS) return;
    float mx = mmv[a * 3 + 0], my = mmv[a * 3 + 1], mz = mmv[a * 3 + 2];
    float px = pos[a * 3 + 0], py = pos[a * 3 + 1], pz = pos[a * 3 + 2];
    float mn = sqrtf(mx * mx + my * my + mz * mz + 1e-9f);
    float4* o = (float4*)packed;
    o[a * 2 + 0] = make_float4(mx, my, mz, px);
    o[a * 2 + 1] = make_float4(py, pz, mn, (float)species[a]);
}

// ---------------- sort pass 1: coarse bucket histogram (LDS-aggregated) ----------------

__global__ __launch_bounds__(1024) void k_bhist(const int* __restrict__ i_idx,
                                                int* __restrict__ bucket_count) {
    __shared__ int h[NBUCK];
    int t = threadIdx.x;
    for (int k = t; k < NBUCK; k += 1024) h[k] = 0;
    __syncthreads();
    int base = blockIdx.x * EPB;
    for (int k = t; k < EPB; k += 1024) {
        int e = base + k;
        if (e < N_EDGES) atomicAdd(&h[i_idx[e] >> 8], 1);
    }
    __syncthreads();
    for (int k = t; k < NBUCK; k += 1024)
        if (h[k]) atomicAdd(&bucket_count[k], h[k]);
}

// ---------------- sort pass 2: scan bucket counts ----------------

__global__ void k_bscan(const int* __restrict__ bucket_count,
                        int* __restrict__ bucket_start, int* __restrict__ bucket_cursor) {
    __shared__ int sd[512];
    int t = threadIdx.x;
    int v0 = (t < NBUCK) ? bucket_count[t] : 0;
    sd[t] = v0;
    __syncthreads();
    for (int off = 1; off < 512; off <<= 1) {
        int v = (t >= off) ? sd[t - off] : 0;
        __syncthreads();
        sd[t] += v;
        __syncthreads();
    }
    if (t < NBUCK) { int ex = sd[t] - v0; bucket_start[t] = ex; bucket_cursor[t] = ex; }
}

// ---------------- sort pass 3: scatter (i,j) pairs into bucket-major order ----------------

__global__ __launch_bounds__(1024) void k_bscatter(const int* __restrict__ i_idx,
                                                   const int* __restrict__ j_idx,
                                                   int* __restrict__ bucket_cursor,
                                                   uint2* __restrict__ ij_sorted) {
    __shared__ int h[NBUCK];
    __shared__ int gbase[NBUCK];
    int t = threadIdx.x;
    for (int k = t; k < NBUCK; k += 1024) h[k] = 0;
    __syncthreads();
    int base = blockIdx.x * EPB;
    for (int k = t; k < EPB; k += 1024) {
        int e = base + k;
        if (e < N_EDGES) atomicAdd(&h[i_idx[e] >> 8], 1);
    }
    __syncthreads();
    for (int k = t; k < NBUCK; k += 1024) {
        int c = h[k];
        gbase[k] = c ? atomicAdd(&bucket_cursor[k], c) : 0;
        h[k] = 0;   // reuse as local cursor
    }
    __syncthreads();
    for (int k = t; k < EPB; k += 1024) {
        int e = base + k;
        if (e < N_EDGES) {
            int i = i_idx[e];
            int b = i >> 8;
            int r = atomicAdd(&h[b], 1);
            ij_sorted[gbase[b] + r] = make_uint2((unsigned)i, (unsigned)j_idx[e]);
        }
    }
}

// ---------------- sort pass 4: exact per-bucket sort in LDS + row_start/counts ----------------

__global__ __launch_bounds__(1024) void k_bsort(const int* __restrict__ bucket_start,
                                                const int* __restrict__ bucket_count,
                                                uint2* __restrict__ ij_sorted,
                                                int* __restrict__ row_start,
                                                int* __restrict__ counts) {
    __shared__ int ac[APB];
    __shared__ int st[APB];
    __shared__ uint2 sp[BCAP];
    int b = blockIdx.x, t = threadIdx.x;
    int estart = bucket_start[b], nb = bucket_count[b];
    if (nb > BCAP) nb = BCAP;   // statistically impossible; guards LDS
    int abase = b * APB;
    if (t < APB) ac[t] = 0;
    __syncthreads();
    for (int k = t; k < nb; k += 1024)
        atomicAdd(&ac[ij_sorted[estart + k].x - abase], 1);
    __syncthreads();
    if (t < APB) st[t] = ac[t];
    __syncthreads();
    for (int off = 1; off < APB; off <<= 1) {
        int v = 0;
        if (t < APB && t >= off) v = st[t - off];
        __syncthreads();
        if (t < APB) st[t] += v;
        __syncthreads();
    }
    if (t < APB) {
        int a = abase + t;
        int ex = st[t] - ac[t];
        if (a < N_ATOMS) { row_start[a] = estart + ex; counts[a] = ac[t]; }
        ac[t] = ex;   // reuse as cursor
    }
    __syncthreads();
    for (int k = t; k < nb; k += 1024) {
        uint2 p = ij_sorted[estart + k];
        int r = atomicAdd(&ac[p.x - abase], 1);
        sp[r] = p;
    }
    __syncthreads();
    for (int k = t; k < nb; k += 1024)
        ij_sorted[estart + k] = sp[k];
}

// ---------------- phase A: per-edge compute, sequential 64B record write (no atomics) ----------------
// record: [0,32) phi f32 x8 | [32,48) bf16 {w1,w2,w3,w4,mnj,w6,w7,rhx} | [48,52) bf16 {rhy,rhz} | pad

__global__ __launch_bounds__(256) void k_edges(
    const float* __restrict__ packed, const float* __restrict__ cheb,
    const uint2* __restrict__ ij_sorted, char* __restrict__ recbuf) {
    int e = blockIdx.x * 256 + threadIdx.x;
    if (e >= N_EDGES) return;
    uint2 p = ij_sorted[e];
    int i = (int)p.x, j = (int)p.y;
    const float4* pk = (const float4*)packed;
    float4 i0 = pk[i * 2 + 0], i1 = pk[i * 2 + 1];
    float4 j0 = pk[j * 2 + 0], j1 = pk[j * 2 + 1];

    float mix = i0.x, miy = i0.y, miz = i0.z;
    float mjx = j0.x, mjy = j0.y, mjz = j0.z;
    float rx = j0.w - i0.w, ry = j1.x - i1.x, rz = j1.y - i1.y;
    float mni = i1.z, mnj = j1.z;
    int spi = (int)i1.w, spj = (int)j1.w;

    float d = sqrtf(rx * rx + ry * ry + rz * rz + 1e-9f);
    float invd = frcp(d);
    float rhx = rx * invd, rhy = ry * invd, rhz = rz * invd;

    float x = d * (1.f / 3.f) - 1.f;
    x = fminf(fmaxf(x, -1.f), 1.f);
    float x2 = 2.f * x;
    float T[12];
    T[0] = 1.f; T[1] = x;
#pragma unroll
    for (int k = 2; k < 12; k++) T[k] = x2 * T[k - 1] - T[k - 2];
    float fcut = (d < 6.f) ? 0.5f * (__cosf(d * 0.52359877559829887f) + 1.f) : 0.f;

    const float* crow = cheb + (spi * 4 + spj) * 96;
    float phi[8];
#pragma unroll
    for (int n = 0; n < 8; n++) {
        const float4* c4 = (const float4*)(crow + n * 12);
        float4 c0 = c4[0], c1 = c4[1], c2 = c4[2];
        float acc = c0.x * T[0] + c0.y * T[1] + c0.z * T[2] + c0.w * T[3];
        acc += c1.x * T[4] + c1.y * T[5] + c1.z * T[6] + c1.w * T[7];
        acc += c2.x * T[8] + c2.y * T[9] + c2.z * T[10] + c2.w * T[11];
        phi[n] = acc * fcut;
    }

    float inv_mni = frcp(mni), inv_mnj = frcp(mnj);
    float mhix = mix * inv_mni, mhiy = miy * inv_mni, mhiz = miz * inv_mni;
    float mhjx = mjx * inv_mnj, mhjy = mjy * inv_mnj, mhjz = mjz * inv_mnj;
    float w1 = mix * mjx + miy * mjy + miz * mjz;
    float dhi = mhix * rhx + mhiy * rhy + mhiz * rhz;
    float dhj = mhjx * rhx + mhjy * rhy + mhjz * rhz;
    float w2 = dhi * dhi, w3 = dhj * dhj;
    float cx = miy * mjz - miz * mjy;
    float cy = miz * mjx - mix * mjz;
    float cz = mix * mjy - miy * mjx;
    float w4 = rhx * cx + rhy * cy + rhz * cz;
    float w6 = (mhix * mhjx + mhiy * mhjy + mhiz * mhjz) * mnj;
    float w7 = mnj * mnj;

    char* rp = recbuf + (size_t)e * 64;
    *(float4*)(rp +  0) = make_float4(phi[0], phi[1], phi[2], phi[3]);
    *(float4*)(rp + 16) = make_float4(phi[4], phi[5], phi[6], phi[7]);
    *(uint4*)(rp + 32) = make_uint4(pack2(w1, w2), pack2(w3, w4),
                                    pack2(mnj, w6), pack2(w7, rhx));
    *(uint4*)(rp + 48) = make_uint4(pack2(rhy, rhz), 0u, 0u, 0u);
}

// ---------------- phase B: 8 lanes/atom, lane s owns phi-column s; streaming reads ----------------

__global__ __launch_bounds__(256) void k_reduce(
    const char* __restrict__ recbuf, const int* __restrict__ row_start,
    const int* __restrict__ counts, float* __restrict__ segbuf) {
    int tid = blockIdx.x * 256 + threadIdx.x;
    int a = tid >> 3;
    int s = tid & 7;
    if (a >= N_ATOMS) return;

    int start = row_start[a], cnt = counts[a];

    float sg0 = 0.f, sg1 = 0.f, sg2 = 0.f, sg3 = 0.f;
    float sg4 = 0.f, sg5 = 0.f, sg6 = 0.f, sg7 = 0.f;
    float vcx = 0.f, vcy = 0.f, vcz = 0.f;

    for (int it = 0; it < cnt; ++it) {
        const char* rp = recbuf + (size_t)(start + it) * 64;
        float phis = *(const float*)(rp + s * 4);
        uint4 wq = *(const uint4*)(rp + 32);
        unsigned rq = *(const unsigned*)(rp + 48);

        float w1 = lo16(wq.x), w2 = hi16(wq.x);
        float w3 = lo16(wq.y), w4 = hi16(wq.y);
        float w5 = lo16(wq.z), w6 = hi16(wq.z);
        float w7 = lo16(wq.w), rhx = hi16(wq.w);
        float rhy = lo16(rq), rhz = hi16(rq);

        sg0 += phis;
        sg1 = fmaf(w1, phis, sg1);
        sg2 = fmaf(w2, phis, sg2);
        sg3 = fmaf(w3, phis, sg3);
        sg4 = fmaf(w4, phis, sg4);
        sg5 = fmaf(w5, phis, sg5);
        sg6 = fmaf(w6, phis, sg6);
        sg7 = fmaf(w7, phis, sg7);
        vcx = fmaf(phis, rhx, vcx);
        vcy = fmaf(phis, rhy, vcy);
        vcz = fmaf(phis, rhz, vcz);
    }

    float* o = segbuf + (size_t)a * 72;
    o[0 * 8 + s] = sg0; o[1 * 8 + s] = sg1; o[2 * 8 + s] = sg2; o[3 * 8 + s] = sg3;
    o[4 * 8 + s] = sg4; o[5 * 8 + s] = sg5; o[6 * 8 + s] = sg6; o[7 * 8 + s] = sg7;
    o[64 + s] = vcx * vcx + vcy * vcy + vcz * vcz;
}

// ---------------- structure MLP: thread=atom, weights via uniform s_load ----------------

__global__ __launch_bounds__(256) void k_struct(
    const float* __restrict__ segbuf, const int* __restrict__ species,
    const int* __restrict__ batch, const float* __restrict__ embt,
    const float* __restrict__ shift,
    const float* __restrict__ Ws1, const float* __restrict__ bs1,
    const float* __restrict__ Ws2, const float* __restrict__ bs2,
    const float* __restrict__ Ws3, const float* __restrict__ bs3,
    float* __restrict__ out) {
    __shared__ float spart[NSTRUCT];
    int t = threadIdx.x;
    if (t < NSTRUCT) spart[t] = 0.f;
    __syncthreads();

    int a = blockIdx.x * 256 + t;
    if (a < N_ATOMS) {
        const float4* sb4 = (const float4*)(segbuf + (size_t)a * 72);
        float4 v0 = sb4[0], v1 = sb4[1];
        float4 v2 = sb4[16], v3 = sb4[17];
        int spi = species[a];
        const float4* e4 = (const float4*)(embt + spi * 16);
        float4 e0 = e4[0], e1 = e4[1], e2 = e4[2], e3 = e4[3];
        float x[32] = {v0.x, v0.y, v0.z, v0.w, v1.x, v1.y, v1.z, v1.w,
                       v2.x, v2.y, v2.z, v2.w, v3.x, v3.y, v3.z, v3.w,
                       e0.x, e0.y, e0.z, e0.w, e1.x, e1.y, e1.z, e1.w,
                       e2.x, e2.y, e2.z, e2.w, e3.x, e3.y, e3.z, e3.w};

        float h1[64];
#pragma unroll
        for (int o = 0; o < 64; o++) h1[o] = bs1[o];
#pragma unroll
        for (int k = 0; k < 32; k++) {
            float xv = x[k];
#pragma unroll
            for (int o = 0; o < 64; o++) h1[o] = fmaf(xv, Ws1[k * 64 + o], h1[o]);
        }
#pragma unroll
        for (int o = 0; o < 64; o++) h1[o] = silu(h1[o]);

        float h2[64];
#pragma unroll
        for (int o = 0; o < 64; o++) h2[o] = bs2[o];
#pragma unroll
        for (int k = 0; k < 64; k++) {
            float xv = h1[k];
#pragma unroll
            for (int o = 0; o < 64; o++) h2[o] = fmaf(xv, Ws2[k * 64 + o], h2[o]);
        }
        float e_struct = bs3[0] + shift[spi];
#pragma unroll
        for (int o = 0; o < 64; o++) e_struct = fmaf(silu(h2[o]), Ws3[o], e_struct);
        atomicAdd(&spart[batch[a]], e_struct);
    }
    __syncthreads();
    if (t < NSTRUCT) {
        float v = spart[t];
        if (v != 0.f) atomicAdd(&out[t], v);
    }
}

// ---------------- magnetic MLP: wave=head (readfirstlane), weights via uniform s_load ----------------

__global__ __launch_bounds__(576) void k_mag(
    const float* __restrict__ segbuf, const float* __restrict__ packed,
    const int* __restrict__ species, const int* __restrict__ batch,
    const float* __restrict__ embt,
    const float* __restrict__ Wm1, const float* __restrict__ bm1,
    const float* __restrict__ Wm2, const float* __restrict__ bm2,
    const float* __restrict__ Wm3, const float* __restrict__ bm3,
    float* __restrict__ out) {
    __shared__ float spart[NSTRUCT];
    int t = threadIdx.x;
    if (t < NSTRUCT) spart[t] = 0.f;
    __syncthreads();

    int h = __builtin_amdgcn_readfirstlane((int)(threadIdx.x >> 6));
    int l = t & 63;
    int a = blockIdx.x * 64 + l;
    if (a < N_ATOMS) {
        int kk = (h <= 5) ? h : (h - 1);
        const float4* sb4 = (const float4*)(segbuf + (size_t)a * 72 + kk * 8);
        float4 s0 = sb4[0], s1 = sb4[1];
        float amp = (h == 0 || h == 5) ? packed[a * 8 + 6] : 1.f;
        int spi = species[a];
        const float4* e4 = (const float4*)(embt + spi * 16);
        float4 e0 = e4[0], e1 = e4[1], e2 = e4[2], e3 = e4[3];
        float x[24] = {s0.x * amp, s0.y * amp, s0.z * amp, s0.w * amp,
                       s1.x * amp, s1.y * amp, s1.z * amp, s1.w * amp,
                       e0.x, e0.y, e0.z, e0.w, e1.x, e1.y, e1.z, e1.w,
                       e2.x, e2.y, e2.z, e2.w, e3.x, e3.y, e3.z, e3.w};

        const float* wb1 = Wm1 + h * 768;
        float hm1[32];
#pragma unroll
        for (int o = 0; o < 32; o++) hm1[o] = bm1[h * 32 + o];
#pragma unroll
        for (int d = 0; d < 24; d++) {
            float xv = x[d];
#pragma unroll
            for (int o = 0; o < 32; o++) hm1[o] = fmaf(xv, wb1[d * 32 + o], hm1[o]);
        }
#pragma unroll
        for (int o = 0; o < 32; o++) hm1[o] = silu(hm1[o]);

        const float* wb2 = Wm2 + h * 1024;
        float h2[32];
#pragma unroll
        for (int o = 0; o < 32; o++) h2[o] = bm2[h * 32 + o];
#pragma unroll
        for (int d = 0; d < 32; d++) {
            float xv = hm1[d];
#pragma unroll
            for (int o = 0; o < 32; o++) h2[o] = fmaf(xv, wb2[d * 32 + o], h2[o]);
        }
        float e_head = bm3[h];
#pragma unroll
        for (int o = 0; o < 32; o++) e_head = fmaf(silu(h2[o]), Wm3[h * 32 + o], e_head);
        atomicAdd(&spart[batch[a]], e_head);
    }
    __syncthreads();
    if (t < NSTRUCT) {
        float v = spart[t];
        if (v != 0.f) atomicAdd(&out[t], v);
    }
}

// ---------------- launch ----------------

extern "C" void kernel_launch(void* const* d_in, const int* in_sizes, int n_in,
                              void* d_out, int out_size, void* d_ws, size_t ws_size,
                              hipStream_t stream) {
    const float* pos   = (const float*)d_in[0];
    const float* mmv   = (const float*)d_in[1];
    const int* species = (const int*)d_in[2];
    const int* i_idx   = (const int*)d_in[3];
    const int* j_idx   = (const int*)d_in[4];
    const int* batch   = (const int*)d_in[5];
    const float* cheb  = (const float*)d_in[6];
    const float* embt  = (const float*)d_in[7];
    const float* shift = (const float*)d_in[8];
    const float* Ws1 = (const float*)d_in[9];
    const float* bs1 = (const float*)d_in[10];
    const float* Ws2 = (const float*)d_in[11];
    const float* bs2 = (const float*)d_in[12];
    const float* Ws3 = (const float*)d_in[13];
    const float* bs3 = (const float*)d_in[14];
    const float* Wm1 = (const float*)d_in[15];
    const float* bm1 = (const float*)d_in[16];
    const float* Wm2 = (const float*)d_in[17];
    const float* bm2 = (const float*)d_in[18];
    const float* Wm3 = (const float*)d_in[19];
    const float* bm3 = (const float*)d_in[20];
    float* out = (float*)d_out;

    char* ws = (char*)d_ws;
    int* counts        = (int*)(ws + 0);         // 400 KB
    int* row_start     = (int*)(ws + 400384);    // 400 KB
    int* bucket_count  = (int*)(ws + 800768);    // 2 KB
    int* bucket_start  = (int*)(ws + 802816);    // 2 KB
    int* bucket_cursor = (int*)(ws + 804864);    // 2 KB
    float* packed      = (float*)(ws + 806912);  // 3.2 MB
    float* segbuf      = (float*)(ws + 4006912); // 28.8 MB
    uint2* ij_sorted   = (uint2*)(ws + 4006912); // 12.8 MB (overlaid on segbuf; dead before k_reduce writes)
    char* recbuf       = ws + 32806912;          // 102.4 MB (end ~135.2 MB)

    const int NB_ATOM = (N_ATOMS + 255) / 256;   // 391
    const int NB_EDGE = (N_EDGES + 255) / 256;   // 6250
    const int NB_A64  = (N_ATOMS + 63) / 64;     // 1563
    const int NB_EPB  = (N_EDGES + EPB - 1) / EPB; // 391

    hipMemsetAsync(bucket_count, 0, NBUCK * sizeof(int), stream);
    hipMemsetAsync(out, 0, NSTRUCT * sizeof(float), stream);

    k_pack<<<NB_ATOM, 256, 0, stream>>>(pos, mmv, species, packed);
    k_bhist<<<NB_EPB, 1024, 0, stream>>>(i_idx, bucket_count);
    k_bscan<<<1, 512, 0, stream>>>(bucket_count, bucket_start, bucket_cursor);
    k_bscatter<<<NB_EPB, 1024, 0, stream>>>(i_idx, j_idx, bucket_cursor, ij_sorted);
    k_bsort<<<NBUCK, 1024, 0, stream>>>(bucket_start, bucket_count, ij_sorted, row_start, counts);
    k_edges<<<NB_EDGE, 256, 0, stream>>>(packed, cheb, ij_sorted, recbuf);
    k_reduce<<<(N_ATOMS * 8 + 255) / 256, 256, 0, stream>>>(recbuf, row_start, counts, segbuf);
    k_struct<<<NB_ATOM, 256, 0, stream>>>(segbuf, species, batch, embt, shift,
                                          Ws1, bs1, Ws2, bs2, Ws3, bs3, out);
    k_mag<<<NB_A64, 576, 0, stream>>>(segbuf, packed, species, batch, embt,
                                      Wm1, bm1, Wm2, bm2, Wm3, bm3, out);
}

// Round 7
// 241.693 us; speedup vs baseline: 1.7754x; 1.2069x over previous
//
#include <hip/hip_runtime.h>
#include <math.h>

#define N_ATOMS 100000
#define N_EDGES 1600000
#define NSTRUCT 64
#define NBUCK 391      // ceil(N_ATOMS/256) buckets of 256 atoms
#define APB 256        // atoms per bucket
#define EPB 4096       // edges per block in bucket passes
#define BCAP 6144      // LDS staging cap per bucket (mean 4092, sigma 64)

__device__ __forceinline__ float frcp(float x) { return __builtin_amdgcn_rcpf(x); }
__device__ __forceinline__ float silu(float v) { return v * frcp(1.f + __expf(-v)); }

__device__ __forceinline__ unsigned pack2(float a, float b) {
    unsigned ua = __float_as_uint(a), ub = __float_as_uint(b);
    ua = (ua + 0x7fffu + ((ua >> 16) & 1u)) >> 16;
    ub = (ub + 0x7fffu + ((ub >> 16) & 1u)) >> 16;
    return ua | (ub << 16);
}
__device__ __forceinline__ float lo16(unsigned u) { return __uint_as_float(u << 16); }
__device__ __forceinline__ float hi16(unsigned u) { return __uint_as_float(u & 0xffff0000u); }

// ---------------- pack atom data: {mx,my,mz,px},{py,pz,mnorm,species} ----------------

__global__ void k_pack(const float* __restrict__ pos, const float* __restrict__ mmv,
                       const int* __restrict__ species, float* __restrict__ packed) {
    int a = blockIdx.x * 256 + threadIdx.x;
    if (a >= N_ATOMS) return;
    float mx = mmv[a * 3 + 0], my = mmv[a * 3 + 1], mz = mmv[a * 3 + 2];
    float px = pos[a * 3 + 0], py = pos[a * 3 + 1], pz = pos[a * 3 + 2];
    float mn = sqrtf(mx * mx + my * my + mz * mz + 1e-9f);
    float4* o = (float4*)packed;
    o[a * 2 + 0] = make_float4(mx, my, mz, px);
    o[a * 2 + 1] = make_float4(py, pz, mn, (float)species[a]);
}

// ---------------- prep: fold emb @ W-layer1 (+bias) per (species/head), species only 4 ----------------
// c1m[(h*4+sp)*32+o] = bm1[h][o] + sum_q emb[sp][q] * Wm1[h][8+q][o]
// c1s[sp*64+o]       = bs1[o]    + sum_q emb[sp][q] * Ws1[16+q][o]

__global__ void k_prep(const float* __restrict__ embt,
                       const float* __restrict__ Wm1, const float* __restrict__ bm1,
                       const float* __restrict__ Ws1, const float* __restrict__ bs1,
                       float* __restrict__ c1m, float* __restrict__ c1s) {
    int tid = blockIdx.x * 256 + threadIdx.x;
    if (tid < 1152) {
        int h = tid >> 7;
        int sp = (tid >> 5) & 3;
        int o = tid & 31;
        float c = bm1[h * 32 + o];
#pragma unroll
        for (int q = 0; q < 16; q++)
            c = fmaf(embt[sp * 16 + q], Wm1[(h * 24 + 8 + q) * 32 + o], c);
        c1m[tid] = c;
    } else if (tid < 1152 + 256) {
        int k = tid - 1152;
        int sp = k >> 6, o = k & 63;
        float c = bs1[o];
#pragma unroll
        for (int q = 0; q < 16; q++)
            c = fmaf(embt[sp * 16 + q], Ws1[(16 + q) * 64 + o], c);
        c1s[k] = c;
    }
}

// ---------------- sort pass 1: coarse bucket histogram (LDS-aggregated) ----------------

__global__ __launch_bounds__(1024) void k_bhist(const int* __restrict__ i_idx,
                                                int* __restrict__ bucket_count) {
    __shared__ int h[NBUCK];
    int t = threadIdx.x;
    for (int k = t; k < NBUCK; k += 1024) h[k] = 0;
    __syncthreads();
    int base = blockIdx.x * EPB;
    for (int k = t; k < EPB; k += 1024) {
        int e = base + k;
        if (e < N_EDGES) atomicAdd(&h[i_idx[e] >> 8], 1);
    }
    __syncthreads();
    for (int k = t; k < NBUCK; k += 1024)
        if (h[k]) atomicAdd(&bucket_count[k], h[k]);
}

// ---------------- sort pass 2: scan bucket counts ----------------

__global__ void k_bscan(const int* __restrict__ bucket_count,
                        int* __restrict__ bucket_start, int* __restrict__ bucket_cursor) {
    __shared__ int sd[512];
    int t = threadIdx.x;
    int v0 = (t < NBUCK) ? bucket_count[t] : 0;
    sd[t] = v0;
    __syncthreads();
    for (int off = 1; off < 512; off <<= 1) {
        int v = (t >= off) ? sd[t - off] : 0;
        __syncthreads();
        sd[t] += v;
        __syncthreads();
    }
    if (t < NBUCK) { int ex = sd[t] - v0; bucket_start[t] = ex; bucket_cursor[t] = ex; }
}

// ---------------- sort pass 3: scatter (i,j) pairs into bucket-major order ----------------

__global__ __launch_bounds__(1024) void k_bscatter(const int* __restrict__ i_idx,
                                                   const int* __restrict__ j_idx,
                                                   int* __restrict__ bucket_cursor,
                                                   uint2* __restrict__ ij_sorted) {
    __shared__ int h[NBUCK];
    __shared__ int gbase[NBUCK];
    int t = threadIdx.x;
    for (int k = t; k < NBUCK; k += 1024) h[k] = 0;
    __syncthreads();
    int base = blockIdx.x * EPB;
    for (int k = t; k < EPB; k += 1024) {
        int e = base + k;
        if (e < N_EDGES) atomicAdd(&h[i_idx[e] >> 8], 1);
    }
    __syncthreads();
    for (int k = t; k < NBUCK; k += 1024) {
        int c = h[k];
        gbase[k] = c ? atomicAdd(&bucket_cursor[k], c) : 0;
        h[k] = 0;   // reuse as local cursor
    }
    __syncthreads();
    for (int k = t; k < EPB; k += 1024) {
        int e = base + k;
        if (e < N_EDGES) {
            int i = i_idx[e];
            int b = i >> 8;
            int r = atomicAdd(&h[b], 1);
            ij_sorted[gbase[b] + r] = make_uint2((unsigned)i, (unsigned)j_idx[e]);
        }
    }
}

// ---------------- sort pass 4: exact per-bucket sort in LDS + row_start/counts ----------------

__global__ __launch_bounds__(1024) void k_bsort(const int* __restrict__ bucket_start,
                                                const int* __restrict__ bucket_count,
                                                uint2* __restrict__ ij_sorted,
                                                int* __restrict__ row_start,
                                                int* __restrict__ counts) {
    __shared__ int ac[APB];
    __shared__ int st[APB];
    __shared__ uint2 sp[BCAP];
    int b = blockIdx.x, t = threadIdx.x;
    int estart = bucket_start[b], nb = bucket_count[b];
    if (nb > BCAP) nb = BCAP;   // statistically impossible; guards LDS
    int abase = b * APB;
    if (t < APB) ac[t] = 0;
    __syncthreads();
    for (int k = t; k < nb; k += 1024)
        atomicAdd(&ac[ij_sorted[estart + k].x - abase], 1);
    __syncthreads();
    if (t < APB) st[t] = ac[t];
    __syncthreads();
    for (int off = 1; off < APB; off <<= 1) {
        int v = 0;
        if (t < APB && t >= off) v = st[t - off];
        __syncthreads();
        if (t < APB) st[t] += v;
        __syncthreads();
    }
    if (t < APB) {
        int a = abase + t;
        int ex = st[t] - ac[t];
        if (a < N_ATOMS) { row_start[a] = estart + ex; counts[a] = ac[t]; }
        ac[t] = ex;   // reuse as cursor
    }
    __syncthreads();
    for (int k = t; k < nb; k += 1024) {
        uint2 p = ij_sorted[estart + k];
        int r = atomicAdd(&ac[p.x - abase], 1);
        sp[r] = p;
    }
    __syncthreads();
    for (int k = t; k < nb; k += 1024)
        ij_sorted[estart + k] = sp[k];
}

// ---------------- phase A: per-edge compute, sequential 64B record write (no atomics) ----------------
// record: [0,32) phi f32 x8 | [32,48) bf16 {w1,w2,w3,w4,mnj,w6,w7,rhx} | [48,52) bf16 {rhy,rhz} | pad

__global__ __launch_bounds__(256) void k_edges(
    const float* __restrict__ packed, const float* __restrict__ cheb,
    const uint2* __restrict__ ij_sorted, char* __restrict__ recbuf) {
    int e = blockIdx.x * 256 + threadIdx.x;
    if (e >= N_EDGES) return;
    uint2 p = ij_sorted[e];
    int i = (int)p.x, j = (int)p.y;
    const float4* pk = (const float4*)packed;
    float4 i0 = pk[i * 2 + 0], i1 = pk[i * 2 + 1];
    float4 j0 = pk[j * 2 + 0], j1 = pk[j * 2 + 1];

    float mix = i0.x, miy = i0.y, miz = i0.z;
    float mjx = j0.x, mjy = j0.y, mjz = j0.z;
    float rx = j0.w - i0.w, ry = j1.x - i1.x, rz = j1.y - i1.y;
    float mni = i1.z, mnj = j1.z;
    int spi = (int)i1.w, spj = (int)j1.w;

    float d = sqrtf(rx * rx + ry * ry + rz * rz + 1e-9f);
    float invd = frcp(d);
    float rhx = rx * invd, rhy = ry * invd, rhz = rz * invd;

    float x = d * (1.f / 3.f) - 1.f;
    x = fminf(fmaxf(x, -1.f), 1.f);
    float x2 = 2.f * x;
    float T[12];
    T[0] = 1.f; T[1] = x;
#pragma unroll
    for (int k = 2; k < 12; k++) T[k] = x2 * T[k - 1] - T[k - 2];
    float fcut = (d < 6.f) ? 0.5f * (__cosf(d * 0.52359877559829887f) + 1.f) : 0.f;

    const float* crow = cheb + (spi * 4 + spj) * 96;
    float phi[8];
#pragma unroll
    for (int n = 0; n < 8; n++) {
        const float4* c4 = (const float4*)(crow + n * 12);
        float4 c0 = c4[0], c1 = c4[1], c2 = c4[2];
        float acc = c0.x * T[0] + c0.y * T[1] + c0.z * T[2] + c0.w * T[3];
        acc += c1.x * T[4] + c1.y * T[5] + c1.z * T[6] + c1.w * T[7];
        acc += c2.x * T[8] + c2.y * T[9] + c2.z * T[10] + c2.w * T[11];
        phi[n] = acc * fcut;
    }

    float inv_mni = frcp(mni), inv_mnj = frcp(mnj);
    float mhix = mix * inv_mni, mhiy = miy * inv_mni, mhiz = miz * inv_mni;
    float mhjx = mjx * inv_mnj, mhjy = mjy * inv_mnj, mhjz = mjz * inv_mnj;
    float w1 = mix * mjx + miy * mjy + miz * mjz;
    float dhi = mhix * rhx + mhiy * rhy + mhiz * rhz;
    float dhj = mhjx * rhx + mhjy * rhy + mhjz * rhz;
    float w2 = dhi * dhi, w3 = dhj * dhj;
    float cx = miy * mjz - miz * mjy;
    float cy = miz * mjx - mix * mjz;
    float cz = mix * mjy - miy * mjx;
    float w4 = rhx * cx + rhy * cy + rhz * cz;
    float w6 = (mhix * mhjx + mhiy * mhjy + mhiz * mhjz) * mnj;
    float w7 = mnj * mnj;

    char* rp = recbuf + (size_t)e * 64;
    *(float4*)(rp +  0) = make_float4(phi[0], phi[1], phi[2], phi[3]);
    *(float4*)(rp + 16) = make_float4(phi[4], phi[5], phi[6], phi[7]);
    *(uint4*)(rp + 32) = make_uint4(pack2(w1, w2), pack2(w3, w4),
                                    pack2(mnj, w6), pack2(w7, rhx));
    *(uint4*)(rp + 48) = make_uint4(pack2(rhy, rhz), 0u, 0u, 0u);
}

// ---------------- phase B: 8 lanes/atom, lane s owns phi-column s; streaming reads ----------------

__global__ __launch_bounds__(256) void k_reduce(
    const char* __restrict__ recbuf, const int* __restrict__ row_start,
    const int* __restrict__ counts, float* __restrict__ segbuf) {
    int tid = blockIdx.x * 256 + threadIdx.x;
    int a = tid >> 3;
    int s = tid & 7;
    if (a >= N_ATOMS) return;

    int start = row_start[a], cnt = counts[a];

    float sg0 = 0.f, sg1 = 0.f, sg2 = 0.f, sg3 = 0.f;
    float sg4 = 0.f, sg5 = 0.f, sg6 = 0.f, sg7 = 0.f;
    float vcx = 0.f, vcy = 0.f, vcz = 0.f;

    for (int it = 0; it < cnt; ++it) {
        const char* rp = recbuf + (size_t)(start + it) * 64;
        float phis = *(const float*)(rp + s * 4);
        uint4 wq = *(const uint4*)(rp + 32);
        unsigned rq = *(const unsigned*)(rp + 48);

        float w1 = lo16(wq.x), w2 = hi16(wq.x);
        float w3 = lo16(wq.y), w4 = hi16(wq.y);
        float w5 = lo16(wq.z), w6 = hi16(wq.z);
        float w7 = lo16(wq.w), rhx = hi16(wq.w);
        float rhy = lo16(rq), rhz = hi16(rq);

        sg0 += phis;
        sg1 = fmaf(w1, phis, sg1);
        sg2 = fmaf(w2, phis, sg2);
        sg3 = fmaf(w3, phis, sg3);
        sg4 = fmaf(w4, phis, sg4);
        sg5 = fmaf(w5, phis, sg5);
        sg6 = fmaf(w6, phis, sg6);
        sg7 = fmaf(w7, phis, sg7);
        vcx = fmaf(phis, rhx, vcx);
        vcy = fmaf(phis, rhy, vcy);
        vcz = fmaf(phis, rhz, vcz);
    }

    float* o = segbuf + (size_t)a * 72;
    o[0 * 8 + s] = sg0; o[1 * 8 + s] = sg1; o[2 * 8 + s] = sg2; o[3 * 8 + s] = sg3;
    o[4 * 8 + s] = sg4; o[5 * 8 + s] = sg5; o[6 * 8 + s] = sg6; o[7 * 8 + s] = sg7;
    o[64 + s] = vcx * vcx + vcy * vcy + vcz * vcz;
}

// ---------------- structure MLP: thread=atom, chunked layer-2, uniform s_load weights ----------------

__global__ __launch_bounds__(256, 4) void k_struct(
    const float* __restrict__ segbuf, const int* __restrict__ species,
    const int* __restrict__ batch, const float* __restrict__ c1s,
    const float* __restrict__ shift,
    const float* __restrict__ Ws1,
    const float* __restrict__ Ws2, const float* __restrict__ bs2,
    const float* __restrict__ Ws3, const float* __restrict__ bs3,
    float* __restrict__ out) {
    __shared__ float spart[NSTRUCT];
    int t = threadIdx.x;
    if (t < NSTRUCT) spart[t] = 0.f;
    __syncthreads();

    int a = blockIdx.x * 256 + t;
    if (a < N_ATOMS) {
        const float4* sb4 = (const float4*)(segbuf + (size_t)a * 72);
        float4 v0 = sb4[0], v1 = sb4[1];
        float4 v2 = sb4[16], v3 = sb4[17];
        int spi = species[a];
        float x[16] = {v0.x, v0.y, v0.z, v0.w, v1.x, v1.y, v1.z, v1.w,
                       v2.x, v2.y, v2.z, v2.w, v3.x, v3.y, v3.z, v3.w};

        const float* cb = c1s + spi * 64;
        float h1[64];
#pragma unroll
        for (int o = 0; o < 64; o++) h1[o] = cb[o];
#pragma unroll
        for (int k = 0; k < 16; k++) {
            float xv = x[k];
#pragma unroll
            for (int o = 0; o < 64; o++) h1[o] = fmaf(xv, Ws1[k * 64 + o], h1[o]);
        }
#pragma unroll
        for (int o = 0; o < 64; o++) h1[o] = silu(h1[o]);

        float e_struct = bs3[0] + shift[spi];
#pragma unroll 1
        for (int cbk = 0; cbk < 4; cbk++) {
            float h2[16];
#pragma unroll
            for (int o = 0; o < 16; o++) h2[o] = bs2[cbk * 16 + o];
#pragma unroll 4
            for (int k = 0; k < 64; k++) {
                float xv = h1[k];
#pragma unroll
                for (int o = 0; o < 16; o++)
                    h2[o] = fmaf(xv, Ws2[k * 64 + cbk * 16 + o], h2[o]);
            }
#pragma unroll
            for (int o = 0; o < 16; o++)
                e_struct = fmaf(silu(h2[o]), Ws3[cbk * 16 + o], e_struct);
        }
        atomicAdd(&spart[batch[a]], e_struct);
    }
    __syncthreads();
    if (t < NSTRUCT) {
        float v = spart[t];
        if (v != 0.f) atomicAdd(&out[t], v);
    }
}

// ---------------- magnetic MLP: grid.y = head (truly uniform), chunked layer-2 ----------------

__global__ __launch_bounds__(256, 4) void k_mag(
    const float* __restrict__ segbuf, const float* __restrict__ packed,
    const int* __restrict__ species, const int* __restrict__ batch,
    const float* __restrict__ c1m,
    const float* __restrict__ Wm1,
    const float* __restrict__ Wm2, const float* __restrict__ bm2,
    const float* __restrict__ Wm3, const float* __restrict__ bm3,
    float* __restrict__ out) {
    __shared__ float spart[NSTRUCT];
    int t = threadIdx.x;
    if (t < NSTRUCT) spart[t] = 0.f;
    __syncthreads();

    int h = blockIdx.y;                 // grid-uniform head index
    int a = blockIdx.x * 256 + t;
    if (a < N_ATOMS) {
        int kk = (h <= 5) ? h : (h - 1);
        const float4* sb4 = (const float4*)(segbuf + (size_t)a * 72 + kk * 8);
        float4 s0 = sb4[0], s1 = sb4[1];
        float amp = (h == 0 || h == 5) ? packed[a * 8 + 6] : 1.f;
        float x[8] = {s0.x * amp, s0.y * amp, s0.z * amp, s0.w * amp,
                      s1.x * amp, s1.y * amp, s1.z * amp, s1.w * amp};
        int spi = species[a];

        const float* cb1 = c1m + (h * 4 + spi) * 32;
        float hm1[32];
#pragma unroll
        for (int o = 0; o < 32; o++) hm1[o] = cb1[o];
        const float* wb1 = Wm1 + h * 768;
#pragma unroll
        for (int d = 0; d < 8; d++) {
            float xv = x[d];
#pragma unroll
            for (int o = 0; o < 32; o++) hm1[o] = fmaf(xv, wb1[d * 32 + o], hm1[o]);
        }
#pragma unroll
        for (int o = 0; o < 32; o++) hm1[o] = silu(hm1[o]);

        const float* wb2 = Wm2 + h * 1024;
        float e_head = bm3[h];
#pragma unroll 1
        for (int cbk = 0; cbk < 2; cbk++) {
            float h2[16];
#pragma unroll
            for (int o = 0; o < 16; o++) h2[o] = bm2[h * 32 + cbk * 16 + o];
#pragma unroll 4
            for (int d = 0; d < 32; d++) {
                float xv = hm1[d];
#pragma unroll
                for (int o = 0; o < 16; o++)
                    h2[o] = fmaf(xv, wb2[d * 32 + cbk * 16 + o], h2[o]);
            }
#pragma unroll
            for (int o = 0; o < 16; o++)
                e_head = fmaf(silu(h2[o]), Wm3[h * 32 + cbk * 16 + o], e_head);
        }
        atomicAdd(&spart[batch[a]], e_head);
    }
    __syncthreads();
    if (t < NSTRUCT) {
        float v = spart[t];
        if (v != 0.f) atomicAdd(&out[t], v);
    }
}

// ---------------- launch ----------------

extern "C" void kernel_launch(void* const* d_in, const int* in_sizes, int n_in,
                              void* d_out, int out_size, void* d_ws, size_t ws_size,
                              hipStream_t stream) {
    const float* pos   = (const float*)d_in[0];
    const float* mmv   = (const float*)d_in[1];
    const int* species = (const int*)d_in[2];
    const int* i_idx   = (const int*)d_in[3];
    const int* j_idx   = (const int*)d_in[4];
    const int* batch   = (const int*)d_in[5];
    const float* cheb  = (const float*)d_in[6];
    const float* embt  = (const float*)d_in[7];
    const float* shift = (const float*)d_in[8];
    const float* Ws1 = (const float*)d_in[9];
    const float* bs1 = (const float*)d_in[10];
    const float* Ws2 = (const float*)d_in[11];
    const float* bs2 = (const float*)d_in[12];
    const float* Ws3 = (const float*)d_in[13];
    const float* bs3 = (const float*)d_in[14];
    const float* Wm1 = (const float*)d_in[15];
    const float* bm1 = (const float*)d_in[16];
    const float* Wm2 = (const float*)d_in[17];
    const float* bm2 = (const float*)d_in[18];
    const float* Wm3 = (const float*)d_in[19];
    const float* bm3 = (const float*)d_in[20];
    float* out = (float*)d_out;

    char* ws = (char*)d_ws;
    int* counts        = (int*)(ws + 0);         // 400 KB
    int* row_start     = (int*)(ws + 400384);    // 400 KB
    int* bucket_count  = (int*)(ws + 800768);    // 2 KB
    int* bucket_start  = (int*)(ws + 802816);    // 2 KB
    int* bucket_cursor = (int*)(ws + 804864);    // 2 KB
    float* c1m         = (float*)(ws + 806912);  // 4.6 KB
    float* c1s         = (float*)(ws + 811520);  // 1 KB
    float* packed      = (float*)(ws + 812544);  // 3.2 MB
    float* segbuf      = (float*)(ws + 4012544); // 28.8 MB
    uint2* ij_sorted   = (uint2*)(ws + 4012544); // 12.8 MB (overlaid on segbuf; dead before k_reduce writes)
    char* recbuf       = ws + 32812544;          // 102.4 MB (end ~135.2 MB)

    const int NB_ATOM = (N_ATOMS + 255) / 256;   // 391
    const int NB_EDGE = (N_EDGES + 255) / 256;   // 6250
    const int NB_EPB  = (N_EDGES + EPB - 1) / EPB; // 391

    hipMemsetAsync(bucket_count, 0, NBUCK * sizeof(int), stream);
    hipMemsetAsync(out, 0, NSTRUCT * sizeof(float), stream);

    k_pack<<<NB_ATOM, 256, 0, stream>>>(pos, mmv, species, packed);
    k_prep<<<6, 256, 0, stream>>>(embt, Wm1, bm1, Ws1, bs1, c1m, c1s);
    k_bhist<<<NB_EPB, 1024, 0, stream>>>(i_idx, bucket_count);
    k_bscan<<<1, 512, 0, stream>>>(bucket_count, bucket_start, bucket_cursor);
    k_bscatter<<<NB_EPB, 1024, 0, stream>>>(i_idx, j_idx, bucket_cursor, ij_sorted);
    k_bsort<<<NBUCK, 1024, 0, stream>>>(bucket_start, bucket_count, ij_sorted, row_start, counts);
    k_edges<<<NB_EDGE, 256, 0, stream>>>(packed, cheb, ij_sorted, recbuf);
    k_reduce<<<(N_ATOMS * 8 + 255) / 256, 256, 0, stream>>>(recbuf, row_start, counts, segbuf);
    k_struct<<<NB_ATOM, 256, 0, stream>>>(segbuf, species, batch, c1s, shift,
                                          Ws1, Ws2, bs2, Ws3, bs3, out);
    dim3 magGrid(NB_ATOM, 9);
    k_mag<<<magGrid, 256, 0, stream>>>(segbuf, packed, species, batch, c1m,
                                       Wm1, Wm2, bm2, Wm3, bm3, out);
}